// Round 3
// baseline (450.619 us; speedup 1.0000x reference)
//
#include <hip/hip_runtime.h>
#include <math.h>

typedef unsigned int u32;

#define NDF 11
#define MAXN 35

// ---------------------------------------------------------------------------
// K1: per-graph MLP, one thread per graph. Weights staged to LDS in natural
// row-major layout; all weight reads are wave-uniform (LDS broadcast).
// nn-branch in f64 (floor-boundary safety); decode branches in f32.
// ---------------------------------------------------------------------------
__global__ __launch_bounds__(256, 2)
void k_mlp(const float* __restrict__ z, const float* __restrict__ tpr,
           const float* __restrict__ lin_w, const float* __restrict__ lin_b,
           const float* __restrict__ nn1_w, const float* __restrict__ nn1_b,
           const float* __restrict__ nn2_w, const float* __restrict__ nn2_b,
           const float* __restrict__ nd1_w, const float* __restrict__ nd1_b,
           const float* __restrict__ nd_g, const float* __restrict__ nd_be,
           const float* __restrict__ nd_rm, const float* __restrict__ nd_rv,
           const float* __restrict__ nd2_w, const float* __restrict__ nd2_b,
           const float* __restrict__ pd1_w, const float* __restrict__ pd1_b,
           const float* __restrict__ pd_g, const float* __restrict__ pd_be,
           const float* __restrict__ pd_rm, const float* __restrict__ pd_rv,
           const float* __restrict__ pd2_w, const float* __restrict__ pd2_b,
           const float* __restrict__ nsc, const float* __restrict__ nsh,
           const float* __restrict__ psc, const float* __restrict__ psh,
           float* __restrict__ nf_g, float* __restrict__ pos_g,
           int* __restrict__ nn_int, float* __restrict__ out_nn, int B)
{
    __shared__ float s_lin[33*64];     // [j][k] natural
    __shared__ float s_w1 [64*64];     // [k][o] natural
    __shared__ float s_nd1[64*64];     // [k][o] natural
    __shared__ float s_pd1[64*64];     // [k][o] natural
    __shared__ float s_nd2[64*NDF];    // [o][j] natural
    __shared__ float s_pd2[64*3];      // [o][j] natural
    __shared__ float s_linb[64], s_n1b[64], s_w2[64];
    __shared__ float s_nd1b[64], s_pd1b[64];
    __shared__ float s_ndsc[64], s_ndbi[64], s_pdsc[64], s_pdbi[64];
    __shared__ float s_nd2b[NDF], s_pd2b[3];

    const int t = threadIdx.x;
    for (int i = t; i < 33*64; i += 256) s_lin[i] = lin_w[i];
    for (int i = t; i < 64*64; i += 256) s_w1[i]  = nn1_w[i];
    for (int i = t; i < 64*64; i += 256) s_nd1[i] = nd1_w[i];
    for (int i = t; i < 64*64; i += 256) s_pd1[i] = pd1_w[i];
    for (int i = t; i < 64*NDF; i += 256) s_nd2[i] = nd2_w[i];
    if (t < 64*3) s_pd2[t] = pd2_w[t];
    if (t < 64) {
        s_linb[t] = lin_b[t];
        s_n1b[t]  = nn1_b[t];
        s_w2[t]   = nn2_w[t];
        s_nd1b[t] = nd1_b[t];
        s_pd1b[t] = pd1_b[t];
        float sc = nd_g[t] / sqrtf(nd_rv[t] + 1e-5f);
        s_ndsc[t] = sc;  s_ndbi[t] = nd_be[t] - nd_rm[t] * sc;
        float sp = pd_g[t] / sqrtf(pd_rv[t] + 1e-5f);
        s_pdsc[t] = sp;  s_pdbi[t] = pd_be[t] - pd_rm[t] * sp;
    }
    if (t < NDF) s_nd2b[t] = nd2_b[t];
    if (t < 3)   s_pd2b[t] = pd2_b[t];
    __syncthreads();

    const int g = blockIdx.x * 256 + t;
    if (g >= B) return;

    float zr[32];
    for (int j = 0; j < 32; j++) zr[j] = z[(size_t)g*32 + j];
    const float tp = tpr[g];

    // ---- h = concat(z, tp) @ lin_w + lin_b   (f64) ----
    double h[64];
    for (int k = 0; k < 64; k++) {
        double a = (double)s_linb[k];
        for (int j = 0; j < 32; j++)
            a = fma((double)zr[j], (double)s_lin[j*64 + k], a);
        a = fma((double)tp, (double)s_lin[32*64 + k], a);
        h[k] = a;
    }

    // ---- num_nodes branch (f64) ----
    double logit = (double)nn2_b[0];
    for (int o = 0; o < 64; o++) {
        double a = (double)s_n1b[o];
        for (int k = 0; k < 64; k++)
            a = fma(h[k], (double)s_w1[k*64 + o], a);
        if (a > 0.0) logit = fma(a, (double)s_w2[o], logit);
    }
    const double sg = 1.0 / (1.0 + exp(-logit));
    const int n = (int)(sg * 30.0 + 5.0);   // positive -> trunc == floor

    // ---- decode branches (f32) ----
    float hf[64];
    for (int k = 0; k < 64; k++) hf[k] = (float)h[k];

    float nf[NDF];
    for (int j = 0; j < NDF; j++) nf[j] = s_nd2b[j];
    float px = s_pd2b[0], py = s_pd2b[1], pz = s_pd2b[2];

    for (int o = 0; o < 64; o++) {
        float a = s_nd1b[o];
        float b = s_pd1b[o];
        for (int k = 0; k < 64; k++) {
            const float hv = hf[k];
            a = fmaf(hv, s_nd1[k*64 + o], a);
            b = fmaf(hv, s_pd1[k*64 + o], b);
        }
        a = a > 0.f ? a : 0.f;
        b = b > 0.f ? b : 0.f;
        const float tn = fmaf(a, s_ndsc[o], s_ndbi[o]);
        const float tq = fmaf(b, s_pdsc[o], s_pdbi[o]);
        for (int j = 0; j < NDF; j++)
            nf[j] = fmaf(tn, s_nd2[o*NDF + j], nf[j]);
        px = fmaf(tq, s_pd2[o*3 + 0], px);
        py = fmaf(tq, s_pd2[o*3 + 1], py);
        pz = fmaf(tq, s_pd2[o*3 + 2], pz);
    }

    const float a_ns = nsc[0], a_nh = nsh[0], a_ps = psc[0], a_ph = psh[0];
    for (int j = 0; j < NDF; j++)
        nf_g[(size_t)g*NDF + j] = fmaf(nf[j], a_ns, a_nh);
    pos_g[(size_t)g*3 + 0] = fmaf(px, a_ps, a_ph);
    pos_g[(size_t)g*3 + 1] = fmaf(py, a_ps, a_ph);
    pos_g[(size_t)g*3 + 2] = fmaf(pz, a_ps, a_ph);
    nn_int[g] = n;
    out_nn[g] = (float)n;        // num_nodes output as f32 (exact)
}

// ---------------------------------------------------------------------------
// Single-block inclusive prefix sum (B = 1024 * chunk).
// ---------------------------------------------------------------------------
__global__ __launch_bounds__(1024)
void k_scan(const int* __restrict__ a, int* __restrict__ C, int B)
{
    __shared__ int sums[1024];
    const int t = threadIdx.x;
    const int chunk = B / 1024;
    const int base = t * chunk;

    int s = 0;
    for (int i = 0; i < chunk; i++) s += a[base + i];
    sums[t] = s;
    __syncthreads();

    if (t == 0) {
        int run = 0;
        for (int i = 0; i < 1024; i++) {
            int tmp = sums[i];
            sums[i] = run;      // exclusive
            run += tmp;
        }
    }
    __syncthreads();

    int run = sums[t];
    for (int i = 0; i < chunk; i++) {
        run += a[base + i];
        C[base + i] = run;      // inclusive
    }
}

// ---------------------------------------------------------------------------
// K2: expansion, one thread per output row (f32 stores). Binary search over
// inclusive cumsum C; rows >= C[B-1] repeat graph B-1 (JAX
// total_repeat_length padding semantics).
// ---------------------------------------------------------------------------
__global__ __launch_bounds__(256)
void k_expand(const int* __restrict__ C, const float* __restrict__ nf_g,
              const float* __restrict__ pos_g, float* __restrict__ out,
              int B, int T)
{
    const int r = blockIdx.x * 256 + threadIdx.x;
    if (r >= T) return;

    int lo = 0, hi = B;
    while (lo < hi) {
        int m = (lo + hi) >> 1;
        if (C[m] <= r) lo = m + 1; else hi = m;
    }
    const int i = lo < B ? lo : B - 1;

    const float* f = nf_g + (size_t)i * NDF;
    float* onf = out + (size_t)r * NDF;
    for (int j = 0; j < NDF; j++) onf[j] = f[j];

    const float* p = pos_g + (size_t)i * 3;
    float* ops = out + (size_t)T * NDF + (size_t)r * 3;
    ops[0] = p[0];
    ops[1] = p[1];
    ops[2] = p[2];
}

// ---------------------------------------------------------------------------
extern "C" void kernel_launch(void* const* d_in, const int* in_sizes, int n_in,
                              void* d_out, int out_size, void* d_ws, size_t ws_size,
                              hipStream_t stream)
{
    const float* z     = (const float*)d_in[0];
    const float* tpr   = (const float*)d_in[1];
    const int    B     = in_sizes[1];          // target_property length
    const int    T     = B * MAXN;

    const float* lin_w = (const float*)d_in[3];
    const float* lin_b = (const float*)d_in[4];
    const float* nn1_w = (const float*)d_in[5];
    const float* nn1_b = (const float*)d_in[6];
    const float* nn2_w = (const float*)d_in[7];
    const float* nn2_b = (const float*)d_in[8];
    const float* nd1_w = (const float*)d_in[9];
    const float* nd1_b = (const float*)d_in[10];
    const float* nd_g  = (const float*)d_in[11];
    const float* nd_be = (const float*)d_in[12];
    const float* nd_rm = (const float*)d_in[13];
    const float* nd_rv = (const float*)d_in[14];
    const float* nd2_w = (const float*)d_in[15];
    const float* nd2_b = (const float*)d_in[16];
    const float* pd1_w = (const float*)d_in[17];
    const float* pd1_b = (const float*)d_in[18];
    const float* pd_g  = (const float*)d_in[19];
    const float* pd_be = (const float*)d_in[20];
    const float* pd_rm = (const float*)d_in[21];
    const float* pd_rv = (const float*)d_in[22];
    const float* pd2_w = (const float*)d_in[23];
    const float* pd2_b = (const float*)d_in[24];
    const float* nsc   = (const float*)d_in[25];
    const float* nsh   = (const float*)d_in[26];
    const float* psc   = (const float*)d_in[27];
    const float* psh   = (const float*)d_in[28];

    float* out = (float*)d_out;

    char* w = (char*)d_ws;
    float* nf_g  = (float*)w;                          // B*11 f32
    float* pos_g = (float*)(w + (size_t)B*NDF*4);      // B*3  f32
    int*   nn_i  = (int*)  (w + (size_t)B*14*4);       // B int
    int*   C     = nn_i + B;                           // B int

    const int nb = B / 256;   // 512 for B=131072

    k_mlp<<<nb, 256, 0, stream>>>(z, tpr, lin_w, lin_b, nn1_w, nn1_b, nn2_w, nn2_b,
                                  nd1_w, nd1_b, nd_g, nd_be, nd_rm, nd_rv, nd2_w, nd2_b,
                                  pd1_w, pd1_b, pd_g, pd_be, pd_rm, pd_rv, pd2_w, pd2_b,
                                  nsc, nsh, psc, psh,
                                  nf_g, pos_g, nn_i, out + (size_t)T*14, B);
    k_scan<<<1, 1024, 0, stream>>>(nn_i, C, B);
    k_expand<<<(T + 255)/256, 256, 0, stream>>>(C, nf_g, pos_g, out, B, T);

    (void)n_in; (void)out_size; (void)ws_size;
}

// Round 4
// 212.738 us; speedup vs baseline: 2.1182x; 2.1182x over previous
//
#include <hip/hip_runtime.h>
#include <math.h>

#define NDF 11
#define MAXN 35

// ---------------------------------------------------------------------------
// k_prep: one-time weight transpose/convert into workspace.
//   lin64 [j][k] f64 (natural), linb64/n1b64/w264 f64,
//   w1t64 [o][k] f64 (transposed), nd1t/pd1t [o][k] f32 (transposed)
// ---------------------------------------------------------------------------
__global__ void k_prep(const float* __restrict__ lin_w, const float* __restrict__ lin_b,
                       const float* __restrict__ nn1_w, const float* __restrict__ nn1_b,
                       const float* __restrict__ nn2_w,
                       const float* __restrict__ nd1_w, const float* __restrict__ pd1_w,
                       double* __restrict__ lin64, double* __restrict__ linb64,
                       double* __restrict__ w1t64, double* __restrict__ n1b64,
                       double* __restrict__ w264,
                       float* __restrict__ nd1t, float* __restrict__ pd1t)
{
    const int i0 = blockIdx.x * 256 + threadIdx.x;   // 16 blocks -> 4096 threads
    for (int i = i0; i < 33*64; i += 4096) lin64[i] = (double)lin_w[i];
    if (i0 < 64) {
        linb64[i0] = (double)lin_b[i0];
        n1b64[i0]  = (double)nn1_b[i0];
        w264[i0]   = (double)nn2_w[i0];
    }
    for (int i = i0; i < 64*64; i += 4096) {
        const int o = i >> 6, k = i & 63;
        const int src = k*64 + o;
        w1t64[i] = (double)nn1_w[src];
        nd1t[i]  = nd1_w[src];
        pd1t[i]  = pd1_w[src];
    }
}

// ---------------------------------------------------------------------------
// k1: phase A (f64) + num_nodes branch (f64). One thread per graph.
// Weights pre-converted to f64 in LDS -> no per-use cvt; b128 broadcast reads.
// ---------------------------------------------------------------------------
__global__ __launch_bounds__(256)
void k1_hnn(const float* __restrict__ z, const float* __restrict__ tpr,
            const double* __restrict__ lin64, const double* __restrict__ linb64,
            const double* __restrict__ w1t64, const double* __restrict__ n1b64,
            const double* __restrict__ w264, const float* __restrict__ nn2_b,
            int* __restrict__ nn_int, float* __restrict__ out_nn, int B)
{
    __shared__ __align__(16) double s_lin[33*64];   // 16896 B
    __shared__ __align__(16) double s_w1[64*64];    // 32768 B
    __shared__ double s_lb[64], s_nb[64], s_w2[64];

    const int t = threadIdx.x;
    for (int i = t; i < 33*64; i += 256) s_lin[i] = lin64[i];
    for (int i = t; i < 64*64; i += 256) s_w1[i]  = w1t64[i];
    if (t < 64) { s_lb[t] = linb64[t]; s_nb[t] = n1b64[t]; s_w2[t] = w264[t]; }
    __syncthreads();

    const int g = blockIdx.x * 256 + t;
    if (g >= B) return;

    const float tp = tpr[g];

    double h[64];
    #pragma unroll
    for (int k = 0; k < 64; k++) h[k] = s_lb[k];

    // phase A, j-outer: 64 independent accumulators, no register-array indexing
    #pragma unroll 1
    for (int j = 0; j < 33; j++) {
        const float xv = (j < 32) ? z[(size_t)g*32 + j] : tp;   // L1-resident after first touch
        const double xd = (double)xv;
        const double2* row = (const double2*)(s_lin + j*64);
        #pragma unroll
        for (int m = 0; m < 32; m++) {
            const double2 w = row[m];
            h[2*m]   = fma(xd, w.x, h[2*m]);
            h[2*m+1] = fma(xd, w.y, h[2*m+1]);
        }
    }

    // num_nodes branch: 4 accumulator chains per output
    double logit = (double)nn2_b[0];
    #pragma unroll 1
    for (int o = 0; o < 64; o++) {
        const double2* col = (const double2*)(s_w1 + o*64);
        double a0 = s_nb[o], a1 = 0.0, a2 = 0.0, a3 = 0.0;
        #pragma unroll
        for (int m = 0; m < 16; m++) {
            const double2 wa = col[2*m];
            const double2 wb = col[2*m+1];
            a0 = fma(h[4*m+0], wa.x, a0);
            a1 = fma(h[4*m+1], wa.y, a1);
            a2 = fma(h[4*m+2], wb.x, a2);
            a3 = fma(h[4*m+3], wb.y, a3);
        }
        const double a = (a0 + a1) + (a2 + a3);
        if (a > 0.0) logit = fma(a, s_w2[o], logit);
    }
    const double sg = 1.0 / (1.0 + exp(-logit));
    const int n = (int)(sg * 30.0 + 5.0);   // positive -> trunc == floor

    nn_int[g] = n;
    out_nn[g] = (float)n;
}

// ---------------------------------------------------------------------------
// k2: decode heads. Recomputes h in f32 (cheaper than shipping it), then
// nd/pd hidden layers with transposed f32 weights (b128 broadcast reads,
// 4 accumulator chains per head output).
// ---------------------------------------------------------------------------
__global__ __launch_bounds__(256)
void k2_dec(const float* __restrict__ z, const float* __restrict__ tpr,
            const float* __restrict__ lin_w, const float* __restrict__ lin_b,
            const float* __restrict__ nd1t, const float* __restrict__ nd1_b,
            const float* __restrict__ nd_g, const float* __restrict__ nd_be,
            const float* __restrict__ nd_rm, const float* __restrict__ nd_rv,
            const float* __restrict__ nd2_w, const float* __restrict__ nd2_b,
            const float* __restrict__ pd1t, const float* __restrict__ pd1_b,
            const float* __restrict__ pd_g, const float* __restrict__ pd_be,
            const float* __restrict__ pd_rm, const float* __restrict__ pd_rv,
            const float* __restrict__ pd2_w, const float* __restrict__ pd2_b,
            const float* __restrict__ nsc, const float* __restrict__ nsh,
            const float* __restrict__ psc, const float* __restrict__ psh,
            float* __restrict__ nf_g, float* __restrict__ pos_g, int B)
{
    __shared__ __align__(16) float s_lin[33*64];    // 8448 B (natural [j][k])
    __shared__ __align__(16) float s_nd1[64*64];    // transposed [o][k]
    __shared__ __align__(16) float s_pd1[64*64];    // transposed [o][k]
    __shared__ float s_nd2[64*NDF], s_pd2[64*3];
    __shared__ float s_lb[64], s_ndb[64], s_pdb[64];
    __shared__ float s_nsc2[64], s_nbi[64], s_psc2[64], s_pbi[64];
    __shared__ float s_nd2b[NDF], s_pd2b[3];

    const int t = threadIdx.x;
    for (int i = t; i < 33*64; i += 256) s_lin[i] = lin_w[i];
    for (int i = t; i < 64*64; i += 256) s_nd1[i] = nd1t[i];
    for (int i = t; i < 64*64; i += 256) s_pd1[i] = pd1t[i];
    for (int i = t; i < 64*NDF; i += 256) s_nd2[i] = nd2_w[i];
    if (t < 64*3) s_pd2[t] = pd2_w[t];
    if (t < 64) {
        s_lb[t]  = lin_b[t];
        s_ndb[t] = nd1_b[t];
        s_pdb[t] = pd1_b[t];
        float sc = nd_g[t] / sqrtf(nd_rv[t] + 1e-5f);
        s_nsc2[t] = sc;  s_nbi[t] = nd_be[t] - nd_rm[t] * sc;
        float sp = pd_g[t] / sqrtf(pd_rv[t] + 1e-5f);
        s_psc2[t] = sp;  s_pbi[t] = pd_be[t] - pd_rm[t] * sp;
    }
    if (t < NDF) s_nd2b[t] = nd2_b[t];
    if (t < 3)   s_pd2b[t] = pd2_b[t];
    __syncthreads();

    const int g = blockIdx.x * 256 + t;
    if (g >= B) return;

    const float tp = tpr[g];

    float hf[64];
    #pragma unroll
    for (int k = 0; k < 64; k++) hf[k] = s_lb[k];

    #pragma unroll 1
    for (int j = 0; j < 33; j++) {
        const float xv = (j < 32) ? z[(size_t)g*32 + j] : tp;
        const float4* row = (const float4*)(s_lin + j*64);
        #pragma unroll
        for (int m = 0; m < 16; m++) {
            const float4 w = row[m];
            hf[4*m+0] = fmaf(xv, w.x, hf[4*m+0]);
            hf[4*m+1] = fmaf(xv, w.y, hf[4*m+1]);
            hf[4*m+2] = fmaf(xv, w.z, hf[4*m+2]);
            hf[4*m+3] = fmaf(xv, w.w, hf[4*m+3]);
        }
    }

    float nf[NDF];
    #pragma unroll
    for (int j = 0; j < NDF; j++) nf[j] = s_nd2b[j];
    float px = s_pd2b[0], py = s_pd2b[1], pz = s_pd2b[2];

    #pragma unroll 1
    for (int o = 0; o < 64; o++) {
        const float4* cn = (const float4*)(s_nd1 + o*64);
        const float4* cp = (const float4*)(s_pd1 + o*64);
        float n0 = s_ndb[o], n1 = 0.f, n2 = 0.f, n3 = 0.f;
        float p0 = s_pdb[o], p1 = 0.f, p2 = 0.f, p3 = 0.f;
        #pragma unroll
        for (int m = 0; m < 16; m++) {
            const float4 wn = cn[m];
            const float4 wp = cp[m];
            n0 = fmaf(hf[4*m+0], wn.x, n0);
            n1 = fmaf(hf[4*m+1], wn.y, n1);
            n2 = fmaf(hf[4*m+2], wn.z, n2);
            n3 = fmaf(hf[4*m+3], wn.w, n3);
            p0 = fmaf(hf[4*m+0], wp.x, p0);
            p1 = fmaf(hf[4*m+1], wp.y, p1);
            p2 = fmaf(hf[4*m+2], wp.z, p2);
            p3 = fmaf(hf[4*m+3], wp.w, p3);
        }
        float a = (n0 + n1) + (n2 + n3); a = a > 0.f ? a : 0.f;
        float b = (p0 + p1) + (p2 + p3); b = b > 0.f ? b : 0.f;
        const float tn = fmaf(a, s_nsc2[o], s_nbi[o]);
        const float tq = fmaf(b, s_psc2[o], s_pbi[o]);
        #pragma unroll
        for (int j = 0; j < NDF; j++)
            nf[j] = fmaf(tn, s_nd2[o*NDF + j], nf[j]);
        px = fmaf(tq, s_pd2[o*3 + 0], px);
        py = fmaf(tq, s_pd2[o*3 + 1], py);
        pz = fmaf(tq, s_pd2[o*3 + 2], pz);
    }

    const float a_ns = nsc[0], a_nh = nsh[0], a_ps = psc[0], a_ph = psh[0];
    #pragma unroll
    for (int j = 0; j < NDF; j++)
        nf_g[(size_t)g*NDF + j] = fmaf(nf[j], a_ns, a_nh);
    pos_g[(size_t)g*3 + 0] = fmaf(px, a_ps, a_ph);
    pos_g[(size_t)g*3 + 1] = fmaf(py, a_ps, a_ph);
    pos_g[(size_t)g*3 + 2] = fmaf(pz, a_ps, a_ph);
}

// ---------------------------------------------------------------------------
// 3-kernel inclusive prefix sum over B elements (B = nb*256).
// ---------------------------------------------------------------------------
__global__ __launch_bounds__(256)
void k_scan1(const int* __restrict__ a, int* __restrict__ part, int* __restrict__ bsum)
{
    __shared__ int s[256];
    const int t = threadIdx.x;
    const int g = blockIdx.x * 256 + t;
    const int v = a[g];
    s[t] = v;
    __syncthreads();
    for (int d = 1; d < 256; d <<= 1) {
        const int x = s[t];
        const int add = (t >= d) ? s[t - d] : 0;
        __syncthreads();
        s[t] = x + add;
        __syncthreads();
    }
    part[g] = s[t];
    if (t == 255) bsum[blockIdx.x] = s[255];
}

__global__ void k_scan2(const int* __restrict__ bsum, int* __restrict__ boff, int nb)
{
    __shared__ int s[1024];
    const int t = threadIdx.x;     // launched with nb threads (nb = 512, pow2)
    const int v = bsum[t];
    s[t] = v;
    __syncthreads();
    for (int d = 1; d < nb; d <<= 1) {
        const int x = s[t];
        const int add = (t >= d) ? s[t - d] : 0;
        __syncthreads();
        s[t] = x + add;
        __syncthreads();
    }
    boff[t] = s[t] - v;            // exclusive
}

__global__ __launch_bounds__(256)
void k_scan3(const int* __restrict__ part, const int* __restrict__ boff, int* __restrict__ C)
{
    const int g = blockIdx.x * 256 + threadIdx.x;
    C[g] = part[g] + boff[blockIdx.x];
}

// ---------------------------------------------------------------------------
// k_expand: 2 rows/thread, rows packed in LDS, fully-coalesced float4 stores.
// Rows >= C[B-1] repeat graph B-1 (JAX total_repeat_length padding).
// ---------------------------------------------------------------------------
__global__ __launch_bounds__(256)
void k_expand(const int* __restrict__ C, const float* __restrict__ nf_g,
              const float* __restrict__ pos_g, float* __restrict__ out,
              int B, int T)
{
    __shared__ __align__(16) float s_nf[512*NDF];   // 22528 B
    __shared__ __align__(16) float s_ps[512*3];     // 6144 B
    const int t = threadIdx.x;
    const int r0 = blockIdx.x * 512 + 2*t;

    int lo = 0, hi = B;
    while (lo < hi) {
        const int m = (lo + hi) >> 1;
        if (C[m] <= r0) lo = m + 1; else hi = m;
    }
    const int i0 = lo < B ? lo : B - 1;
    const int i1 = ((r0 + 1) >= C[i0] && i0 < B - 1) ? i0 + 1 : i0;

    #pragma unroll
    for (int j = 0; j < NDF; j++) {
        s_nf[(2*t)*NDF + j]     = nf_g[(size_t)i0*NDF + j];
        s_nf[(2*t + 1)*NDF + j] = nf_g[(size_t)i1*NDF + j];
    }
    #pragma unroll
    for (int j = 0; j < 3; j++) {
        s_ps[(2*t)*3 + j]     = pos_g[(size_t)i0*3 + j];
        s_ps[(2*t + 1)*3 + j] = pos_g[(size_t)i1*3 + j];
    }
    __syncthreads();

    float4* onf = (float4*)(out + (size_t)blockIdx.x * 512 * NDF);
    const float4* snf = (const float4*)s_nf;
    #pragma unroll
    for (int q = 0; q < 6; q++) {
        const int idx = q*256 + t;
        if (idx < 512*NDF/4) onf[idx] = snf[idx];    // 1408 float4
    }
    float4* ops = (float4*)(out + (size_t)T*NDF + (size_t)blockIdx.x * 512 * 3);
    const float4* sps = (const float4*)s_ps;
    #pragma unroll
    for (int q = 0; q < 2; q++) {
        const int idx = q*256 + t;
        if (idx < 384) ops[idx] = sps[idx];          // 384 float4
    }
}

// ---------------------------------------------------------------------------
extern "C" void kernel_launch(void* const* d_in, const int* in_sizes, int n_in,
                              void* d_out, int out_size, void* d_ws, size_t ws_size,
                              hipStream_t stream)
{
    const float* z     = (const float*)d_in[0];
    const float* tpr   = (const float*)d_in[1];
    const int    B     = in_sizes[1];          // target_property length
    const int    T     = B * MAXN;

    const float* lin_w = (const float*)d_in[3];
    const float* lin_b = (const float*)d_in[4];
    const float* nn1_w = (const float*)d_in[5];
    const float* nn1_b = (const float*)d_in[6];
    const float* nn2_w = (const float*)d_in[7];
    const float* nn2_b = (const float*)d_in[8];
    const float* nd1_w = (const float*)d_in[9];
    const float* nd1_b = (const float*)d_in[10];
    const float* nd_g  = (const float*)d_in[11];
    const float* nd_be = (const float*)d_in[12];
    const float* nd_rm = (const float*)d_in[13];
    const float* nd_rv = (const float*)d_in[14];
    const float* nd2_w = (const float*)d_in[15];
    const float* nd2_b = (const float*)d_in[16];
    const float* pd1_w = (const float*)d_in[17];
    const float* pd1_b = (const float*)d_in[18];
    const float* pd_g  = (const float*)d_in[19];
    const float* pd_be = (const float*)d_in[20];
    const float* pd_rm = (const float*)d_in[21];
    const float* pd_rv = (const float*)d_in[22];
    const float* pd2_w = (const float*)d_in[23];
    const float* pd2_b = (const float*)d_in[24];
    const float* nsc   = (const float*)d_in[25];
    const float* nsh   = (const float*)d_in[26];
    const float* psc   = (const float*)d_in[27];
    const float* psh   = (const float*)d_in[28];

    float* out = (float*)d_out;

    // workspace layout (256B-aligned slices)
    char* w = (char*)d_ws;
    size_t off = 0;
    auto take = [&](size_t bytes) { void* p = w + off; off = (off + bytes + 255) & ~(size_t)255; return p; };

    double* lin64  = (double*)take(33*64*sizeof(double));
    double* linb64 = (double*)take(64*sizeof(double));
    double* w1t64  = (double*)take(64*64*sizeof(double));
    double* n1b64  = (double*)take(64*sizeof(double));
    double* w264   = (double*)take(64*sizeof(double));
    float*  nd1t   = (float*)take(64*64*sizeof(float));
    float*  pd1t   = (float*)take(64*64*sizeof(float));
    float*  nf_g   = (float*)take((size_t)B*NDF*sizeof(float));
    float*  pos_g  = (float*)take((size_t)B*3*sizeof(float));
    int*    nn_i   = (int*)take((size_t)B*sizeof(int));
    int*    part   = (int*)take((size_t)B*sizeof(int));
    int*    bsum   = (int*)take(4096*sizeof(int));
    int*    boff   = (int*)take(4096*sizeof(int));
    int*    C      = (int*)take((size_t)B*sizeof(int));

    const int nb = B / 256;   // 512 for B=131072

    k_prep<<<16, 256, 0, stream>>>(lin_w, lin_b, nn1_w, nn1_b, nn2_w, nd1_w, pd1_w,
                                   lin64, linb64, w1t64, n1b64, w264, nd1t, pd1t);

    k1_hnn<<<nb, 256, 0, stream>>>(z, tpr, lin64, linb64, w1t64, n1b64, w264, nn2_b,
                                   nn_i, out + (size_t)T*14, B);

    k2_dec<<<nb, 256, 0, stream>>>(z, tpr, lin_w, lin_b,
                                   nd1t, nd1_b, nd_g, nd_be, nd_rm, nd_rv, nd2_w, nd2_b,
                                   pd1t, pd1_b, pd_g, pd_be, pd_rm, pd_rv, pd2_w, pd2_b,
                                   nsc, nsh, psc, psh, nf_g, pos_g, B);

    k_scan1<<<nb, 256, 0, stream>>>(nn_i, part, bsum);
    k_scan2<<<1, nb, 0, stream>>>(bsum, boff, nb);
    k_scan3<<<nb, 256, 0, stream>>>(part, boff, C);

    k_expand<<<T/512, 256, 0, stream>>>(C, nf_g, pos_g, out, B, T);

    (void)n_in; (void)out_size; (void)ws_size;
}